// Round 1
// baseline (143.117 us; speedup 1.0000x reference)
//
#include <hip/hip_runtime.h>

// CAttention on MI355X (gfx950). Inputs f32, output f32.
// Q = box3(x)*log2(e), K = V = normalize(x+EPS), softmax over keys, per batch.
// Round 16: R15 (49.7us flash) + 1-barrier K-loop. sP moved out of the sK alias into a
// per-wave-private, XOR-swizzled 4K region (h=0/1 time-share the same rows; per-wave DS
// in-order). bar2 deleted; next-tile DMA issued right after the sole barrier (window now
// covers QK+softmax+PV); s_setprio(1) around MFMA clusters (waves now phase-skew).
// LDS 73728 B -> still 2 blocks/CU.
// ws: kmat bf16 @0 | kT bf16 @4M | xbT bf16 @8M | lsum f32 @12M | opart bf16 @13M.

typedef short bf16x8 __attribute__((ext_vector_type(8)));
typedef float f32x4 __attribute__((ext_vector_type(4)));
typedef unsigned short u16x8 __attribute__((ext_vector_type(8)));
typedef unsigned int u32x2 __attribute__((ext_vector_type(2)));

#define L2E 1.4426950408889634f

__device__ __forceinline__ unsigned short f2bf(float f) {
    unsigned int u;
    __builtin_memcpy(&u, &f, 4);
    u = u + 0x7FFFu + ((u >> 16) & 1u);   // RNE
    return (unsigned short)(u >> 16);
}
__device__ __forceinline__ float bf2f(unsigned short h) {
    unsigned int u = ((unsigned int)h) << 16;
    float f;
    __builtin_memcpy(&f, &u, 4);
    return f;
}
__device__ __forceinline__ unsigned int pk_bf16(float a, float b) {
    unsigned int ua, ub;
    __builtin_memcpy(&ua, &a, 4);
    __builtin_memcpy(&ub, &b, 4);
    return ((ua + 0x8000u) >> 16) | ((ub + 0x8000u) & 0xFFFF0000u);
}
// async global->LDS, 16B/lane; lptr wave-uniform (HW dst = lptr + lane*16)
__device__ __forceinline__ void gl_lds16(const unsigned short* g, unsigned short* l) {
    __builtin_amdgcn_global_load_lds(
        (const __attribute__((address_space(1))) unsigned int*)g,
        (__attribute__((address_space(3))) unsigned int*)l, 16, 0, 0);
}

// ---------------- K1: fused prep: inv (in-block) + kmat/kT (chunk-swizzled) + xbT --------
// grid (64 p, 4 b) x 256: block = one p-row (64 q), all 128 c.
__global__ void prep(const float* __restrict__ x,
                     unsigned short* __restrict__ kmat,
                     unsigned short* __restrict__ kT,
                     unsigned short* __restrict__ xbT) {
    const int p = blockIdx.x, b = blockIdx.y;
    const int t = threadIdx.x, wave = t >> 6, lane = t & 63;

    __shared__ float sX[8][3][66];
    __shared__ float sMidT[64 * 132];     // [q][c], f32, stride 132
    __shared__ __align__(16) unsigned short sQ[64 * 136];
    __shared__ float sqp[256];
    __shared__ float sInv[64];

    float sqacc = 0.f;
    for (int c0 = 0; c0 < 128; c0 += 8) {
        __syncthreads();
#pragma unroll
        for (int i = 0; i < 6; i++) {                 // 24 coalesced row loads
            int pair = wave * 6 + i;
            int cc = pair / 3, r = pair - cc * 3;
            int pp = p + r - 1;
            float v = 0.f;
            if ((unsigned)pp < 64u)
                v = x[((size_t)b * 128 + c0 + cc) * 4096 + pp * 64 + lane];
            sX[cc][r][1 + lane] = v;
        }
        if (t < 48) {                                 // zero q-borders
            int cc = t / 6, rr = (t % 6) >> 1, side = t & 1;
            sX[cc][rr][side * 65] = 0.f;
        }
        __syncthreads();
#pragma unroll
        for (int j = 0; j < 2; j++) {
            int cc = wave * 2 + j;
            float mid = sX[cc][1][1 + lane] + 1e-7f;
            sMidT[lane * 132 + c0 + cc] = mid;
            sqacc += mid * mid;
            float sbox = 0.f;
#pragma unroll
            for (int r = 0; r < 3; r++)
                sbox += sX[cc][r][lane] + sX[cc][r][lane + 1] + sX[cc][r][lane + 2];
            sQ[lane * 136 + c0 + cc] = f2bf(sbox * L2E);
        }
    }
    sqp[t] = sqacc;
    __syncthreads();
    if (t < 64)
        sInv[t] = rsqrtf(sqp[t] + sqp[64 + t] + sqp[128 + t] + sqp[192 + t]);
    __syncthreads();

    // xbT rows: raw
#pragma unroll
    for (int i = 0; i < 4; i++) {
        int u = i * 256 + t, row = u >> 4, g = u & 15;
        *(bf16x8*)(xbT + ((size_t)b * 4096 + p * 64 + row) * 128 + g * 8) =
            *(const bf16x8*)(sQ + row * 136 + g * 8);
    }
    // kmat rows: 16B chunk G stored at G ^ (q&15)  (key&15 == q&15)
#pragma unroll
    for (int i = 0; i < 4; i++) {
        int u = i * 256 + t, q = u >> 4, G = u & 15;
        float iv = sInv[q];
        f32x4 a = *(const f32x4*)(sMidT + q * 132 + G * 8);
        f32x4 c = *(const f32x4*)(sMidT + q * 132 + G * 8 + 4);
        unsigned int w[4];
        w[0] = pk_bf16(a[0] * iv, a[1] * iv);
        w[1] = pk_bf16(a[2] * iv, a[3] * iv);
        w[2] = pk_bf16(c[0] * iv, c[1] * iv);
        w[3] = pk_bf16(c[2] * iv, c[3] * iv);
        int Gs = G ^ (q & 15);
        *(uint4*)(kmat + ((size_t)b * 4096 + p * 64 + q) * 128 + Gs * 8) =
            make_uint4(w[0], w[1], w[2], w[3]);
    }
    // kT rows: within each 64-key tile, 8-key chunk h stored at h ^ (c&7)
#pragma unroll
    for (int i = 0; i < 2; i++) {
        int u = i * 256 + t, cl = u >> 2, qg = u & 3;
        unsigned int w[8];
#pragma unroll
        for (int j = 0; j < 8; j++) {
            int ql = qg * 16 + j * 2;
            w[j] = pk_bf16(sMidT[ql * 132 + cl] * sInv[ql],
                           sMidT[(ql + 1) * 132 + cl] * sInv[ql + 1]);
        }
        unsigned short* dst = kT + ((size_t)b * 128 + cl) * 4096 + p * 64;
        int h0 = (qg * 2) ^ (cl & 7), h1 = (qg * 2 + 1) ^ (cl & 7);
        *(uint4*)(dst + h0 * 8) = make_uint4(w[0], w[1], w[2], w[3]);
        *(uint4*)(dst + h1 * 8) = make_uint4(w[4], w[5], w[6], w[7]);
    }
}

// ---------------- K2: split-K flash, 1 barrier/iter, private swizzled sP -----------------
#define BUF_STRIDE 16384               // u16: sK 8192 + sV 8192
#define SP_BASE    32768               // u16: sP 64 rows x 64 (per-wave 16 rows, h-shared)
#define SMEM_ELEMS 36864               // u16 = 73728 B -> 2 blocks/CU

__global__ void __launch_bounds__(256, 2) flash_attn(
        const unsigned short* __restrict__ kmat,
        const unsigned short* __restrict__ kT,
        const unsigned short* __restrict__ xbT,
        unsigned short* __restrict__ opart,
        float* __restrict__ lsum,
        int nsplit, int qbshift) {
    const int combo = blockIdx.x & (4 * nsplit - 1);
    const int qb = blockIdx.x >> qbshift;        // 128-query tile, 0..31
    const int b = combo & 3, split = combo >> 2;
    const int nk = 4096 / nsplit, NIT = nk >> 6, kt_base = split * nk;
    const int t = threadIdx.x;
    const int wave = t >> 6, lane = t & 63;
    const int l16 = lane & 15, quad = lane >> 4;

    __shared__ __align__(16) unsigned short smem[SMEM_ELEMS];

    // Q frags (B-operand of S^T): B[n=q=l16][k=c=quad*8+j]
    bf16x8 aq[2][4];
#pragma unroll
    for (int h = 0; h < 2; h++) {
        const unsigned short* xq =
            xbT + ((size_t)b * 4096 + qb * 128 + wave * 32 + h * 16 + l16) * 128 + quad * 8;
#pragma unroll
        for (int cc = 0; cc < 4; cc++) aq[h][cc] = *(const bf16x8*)(xq + cc * 32);
    }

    f32x4 o[2][8];
#pragma unroll
    for (int h = 0; h < 2; h++)
#pragma unroll
        for (int n = 0; n < 8; n++) o[h][n] = (f32x4){0.f, 0.f, 0.f, 0.f};
    float rs[2] = {0.f, 0.f};

    const unsigned short* kmb = kmat + (size_t)b * 4096 * 128;
    const unsigned short* ktb = kT + (size_t)b * 128 * 4096;

    // preload tile 0 into buffer 0
    {
        const unsigned short* gK = kmb + (size_t)kt_base * 128;
#pragma unroll
        for (int i = 0; i < 4; i++) {
            int e = i * 2048 + t * 8;
            gl_lds16(gK + e, smem + i * 2048 + wave * 512);
            gl_lds16(ktb + (size_t)(e >> 6) * 4096 + kt_base + (e & 63),
                     smem + 8192 + i * 2048 + wave * 512);
        }
    }

    // per-wave-private sP row base: row = wave*16 + l16, stride 64 u16 (128 B)
    unsigned short* const sP = smem + SP_BASE + (wave * 16 + l16) * 64;

    for (int it = 0; it < NIT; it++) {
        const int base = (it & 1) * BUF_STRIDE;
        unsigned short* sK = smem + base;                 // [64 keys][128], swizzled chunks
        unsigned short* sV = smem + base + 8192;          // [128 c][64], swizzled chunks

        // sole barrier: drains this tile's DMA (own vmcnt(0)); all waves past it ->
        // all reads of the OTHER buffer (prev iter) retired -> safe to DMA into it.
        __syncthreads();

        // issue next tile's DMA immediately: latency window = QK + softmax + PV
        if (it + 1 < NIT) {
            const int kt0 = kt_base + (it + 1) * 64;
            unsigned short* nb = smem + ((it + 1) & 1) * BUF_STRIDE;
            const unsigned short* gK = kmb + (size_t)kt0 * 128;
#pragma unroll
            for (int i = 0; i < 4; i++) {
                int e = i * 2048 + t * 8;
                gl_lds16(gK + e, nb + i * 2048 + wave * 512);
                gl_lds16(ktb + (size_t)(e >> 6) * 4096 + kt0 + (e & 63),
                         nb + 8192 + i * 2048 + wave * 512);
            }
        }

        // S^T = K Q^T: lane holds S^T[key = k4*16 + quad*4 + r][q = l16]
        f32x4 s[2][4];
#pragma unroll
        for (int h = 0; h < 2; h++)
#pragma unroll
            for (int k4 = 0; k4 < 4; k4++) s[h][k4] = (f32x4){0.f, 0.f, 0.f, 0.f};
        __builtin_amdgcn_s_setprio(1);
#pragma unroll
        for (int cc = 0; cc < 4; cc++) {
#pragma unroll
            for (int k4 = 0; k4 < 4; k4++) {
                bf16x8 ak = *(const bf16x8*)(sK + (k4 * 16 + l16) * 128 +
                                             (((cc * 4 + quad) ^ l16) * 8));
                s[0][k4] = __builtin_amdgcn_mfma_f32_16x16x32_bf16(ak, aq[0][cc], s[0][k4], 0, 0, 0);
                s[1][k4] = __builtin_amdgcn_mfma_f32_16x16x32_bf16(ak, aq[1][cc], s[1][k4], 0, 0, 0);
            }
        }
        __builtin_amdgcn_s_setprio(0);

        // p = 2^s; lane-local row-sum; b64-pack consecutive keys -> private sP.
        // h=0/1 time-share the same sP row (per-wave DS ops are in-order).
        // 16B-slot XOR swizzle (slot ^ (l16&7)): write b64 and read b128 both at bank-min.
        bf16x8 pa[2][2];
#pragma unroll
        for (int h = 0; h < 2; h++) {
#pragma unroll
            for (int k4 = 0; k4 < 4; k4++) {
                float p0 = __builtin_amdgcn_exp2f(s[h][k4][0]);
                float p1 = __builtin_amdgcn_exp2f(s[h][k4][1]);
                float p2 = __builtin_amdgcn_exp2f(s[h][k4][2]);
                float p3 = __builtin_amdgcn_exp2f(s[h][k4][3]);
                rs[h] += (p0 + p1) + (p2 + p3);
                u32x2 d;
                d[0] = pk_bf16(p0, p1);
                d[1] = pk_bf16(p2, p3);
                *(u32x2*)(sP + ((k4 * 2 + (quad >> 1)) ^ (l16 & 7)) * 8 + (quad & 1) * 4) = d;
            }
            asm volatile("" ::: "memory");
#pragma unroll
            for (int kc = 0; kc < 2; kc++)
                pa[h][kc] = *(const bf16x8*)(sP + ((kc * 4 + quad) ^ (l16 & 7)) * 8);
            asm volatile("" ::: "memory");
        }

        // O += P V : swizzled sV chunk read (c&7 == l16&7)
        __builtin_amdgcn_s_setprio(1);
#pragma unroll
        for (int kc = 0; kc < 2; kc++)
#pragma unroll
            for (int n = 0; n < 8; n++) {
                bf16x8 bv = *(const bf16x8*)(sV + (n * 16 + l16) * 64 +
                                             (((kc * 4 + quad) ^ (l16 & 7)) * 8));
                o[0][n] = __builtin_amdgcn_mfma_f32_16x16x32_bf16(pa[0][kc], bv, o[0][n], 0, 0, 0);
                o[1][n] = __builtin_amdgcn_mfma_f32_16x16x32_bf16(pa[1][kc], bv, o[1][n], 0, 0, 0);
            }
        __builtin_amdgcn_s_setprio(0);
    }

    // row-sums reduce across quads; store lsum
#pragma unroll
    for (int h = 0; h < 2; h++) {
        rs[h] += __shfl_xor(rs[h], 16);
        rs[h] += __shfl_xor(rs[h], 32);
    }
    if (lane < 16) {
#pragma unroll
        for (int h = 0; h < 2; h++)
            lsum[(size_t)(split * 4 + b) * 4096 + qb * 128 + wave * 32 + h * 16 + lane] = rs[h];
    }

    // single-pass bf16 epilogue: sO [128 c][136] u16 = 17408 (aliases smem)
    __syncthreads();
    unsigned short* sO = smem;
    unsigned int* sO32 = (unsigned int*)smem;
#pragma unroll
    for (int h = 0; h < 2; h++)
#pragma unroll
        for (int n = 0; n < 8; n++) {
            int c = n * 16 + l16;
            int q = wave * 32 + h * 16 + quad * 4;     // even -> >>1 exact
            sO32[(c * 136 + q) >> 1] = pk_bf16(o[h][n][0], o[h][n][1]);
            sO32[(c * 136 + q + 2) >> 1] = pk_bf16(o[h][n][2], o[h][n][3]);
        }
    __syncthreads();
#pragma unroll
    for (int i = 0; i < 8; i++) {
        int u = i * 256 + t, c = u >> 4, chunk = u & 15;
        *(uint4*)(opart + ((size_t)(split * 4 + b) * 128 + c) * 4096 + qb * 128 + chunk * 8) =
            *(const uint4*)(sO + c * 136 + chunk * 8);
    }
}

// ---------------- K3: combine splits + mask blend ----------------------------------------
// grid (64 qb64, 4 b, 2 cz) x 256: block = 64 q x 64 c.
__global__ void combine(const unsigned short* __restrict__ opart,
                        const float* __restrict__ lsum,
                        const float* __restrict__ x,
                        const float* __restrict__ mask,
                        float* __restrict__ out, int S) {
    const int qb = blockIdx.x, b = blockIdx.y, cz = blockIdx.z, t = threadIdx.x;
    __shared__ float Linv[64];
    if (t < 64) {
        float L = 0.f;
        for (int s2 = 0; s2 < S; s2++)
            L += lsum[(size_t)(s2 * 4 + b) * 4096 + qb * 64 + t];
        Linv[t] = 1.f / fmaxf(L, 1e-37f);
    }
    __syncthreads();
#pragma unroll
    for (int i = 0; i < 2; i++) {
        int u = i * 256 + t, c = cz * 64 + (u >> 3), qc = u & 7;
        size_t qoff = (size_t)qb * 64 + qc * 8;
        float acc[8] = {0.f, 0.f, 0.f, 0.f, 0.f, 0.f, 0.f, 0.f};
        for (int s2 = 0; s2 < S; s2++) {
            u16x8 pv = *(const u16x8*)(opart + ((size_t)(s2 * 4 + b) * 128 + c) * 4096 + qoff);
#pragma unroll
            for (int j = 0; j < 8; j++) acc[j] += bf2f(pv[j]);
        }
        const float* xr = x + ((size_t)b * 128 + c) * 4096 + qoff;
        const float* mr = mask + (size_t)b * 4096 + qoff;
        float* outr = out + ((size_t)b * 128 + c) * 4096 + qoff;
#pragma unroll
        for (int half = 0; half < 2; half++) {
            f32x4 xv = *(const f32x4*)(xr + half * 4);
            f32x4 mv = *(const f32x4*)(mr + half * 4);
            f32x4 res;
#pragma unroll
            for (int j = 0; j < 4; j++)
                res[j] = acc[half * 4 + j] * Linv[qc * 8 + half * 4 + j] *
                         (1.f - mv[j]) * (1.f / 9.f) + xv[j] * mv[j];
            *(f32x4*)(outr + half * 4) = res;
        }
    }
}

extern "C" void kernel_launch(void* const* d_in, const int* in_sizes, int n_in,
                              void* d_out, int out_size, void* d_ws, size_t ws_size,
                              hipStream_t stream) {
    const float* x = (const float*)d_in[0];     // f32 (4,128,64,64)
    const float* mask = (const float*)d_in[1];  // f32 (4,1,64,64)
    float* out = (float*)d_out;                 // f32 (4,128,64,64)
    char* ws = (char*)d_ws;
    unsigned short* kmat = (unsigned short*)(ws);
    unsigned short* kT   = (unsigned short*)(ws + (size_t)4 * 1024 * 1024);
    unsigned short* xbT  = (unsigned short*)(ws + (size_t)8 * 1024 * 1024);
    float* lsum          = (float*)(ws + (size_t)12 * 1024 * 1024);
    unsigned short* opart = (unsigned short*)(ws + (size_t)13 * 1024 * 1024);

    // ws need: 13 MiB + S*4 MiB
    int S, qbshift;
    if (ws_size >= (size_t)29 * 1024 * 1024)      { S = 4; qbshift = 4; }
    else if (ws_size >= (size_t)21 * 1024 * 1024) { S = 2; qbshift = 3; }
    else return;

    prep<<<dim3(64, 4), 256, 0, stream>>>(x, kmat, kT, xbT);
    flash_attn<<<dim3(32 * 4 * S), 256, 0, stream>>>(kmat, kT, xbT, opart, lsum, S, qbshift);
    combine<<<dim3(64, 4, 2), 256, 0, stream>>>(opart, lsum, x, mask, out, S);
}

// Round 2
// 114.860 us; speedup vs baseline: 1.2460x; 1.2460x over previous
//
#include <hip/hip_runtime.h>

// CAttention on MI355X (gfx950). Inputs f32, output f32.
// Q = box3(x)*log2(e), K = V = normalize(x+EPS), softmax over keys, per batch.
// Round 17: flash unchanged (46.2us, verified). prep rewritten: 512 threads (8 waves),
// 8x16-channel chunks (was 16x8), double-buffered sX filled via async global_load_lds
// (width=4, one 256B row per wave-issue), 1 barrier/chunk, DMA for chunk k+1 issued
// right after the barrier and hidden under chunk k's compute. combine: S=4 split loads
// fully unrolled (4 independent loads in flight).
// ws: kmat bf16 @0 | kT bf16 @4M | xbT bf16 @8M | lsum f32 @12M | opart bf16 @13M.

typedef short bf16x8 __attribute__((ext_vector_type(8)));
typedef float f32x4 __attribute__((ext_vector_type(4)));
typedef unsigned short u16x8 __attribute__((ext_vector_type(8)));
typedef unsigned int u32x2 __attribute__((ext_vector_type(2)));

#define L2E 1.4426950408889634f

__device__ __forceinline__ unsigned short f2bf(float f) {
    unsigned int u;
    __builtin_memcpy(&u, &f, 4);
    u = u + 0x7FFFu + ((u >> 16) & 1u);   // RNE
    return (unsigned short)(u >> 16);
}
__device__ __forceinline__ float bf2f(unsigned short h) {
    unsigned int u = ((unsigned int)h) << 16;
    float f;
    __builtin_memcpy(&f, &u, 4);
    return f;
}
__device__ __forceinline__ unsigned int pk_bf16(float a, float b) {
    unsigned int ua, ub;
    __builtin_memcpy(&ua, &a, 4);
    __builtin_memcpy(&ub, &b, 4);
    return ((ua + 0x8000u) >> 16) | ((ub + 0x8000u) & 0xFFFF0000u);
}
// async global->LDS, 16B/lane; lptr wave-uniform (HW dst = lptr + lane*16)
__device__ __forceinline__ void gl_lds16(const unsigned short* g, unsigned short* l) {
    __builtin_amdgcn_global_load_lds(
        (const __attribute__((address_space(1))) unsigned int*)g,
        (__attribute__((address_space(3))) unsigned int*)l, 16, 0, 0);
}
// async global->LDS, 4B/lane; g is per-lane, l wave-uniform (HW dst = l + lane*4)
__device__ __forceinline__ void gl_lds4(const float* g, float* l) {
    __builtin_amdgcn_global_load_lds(
        (const __attribute__((address_space(1))) unsigned int*)g,
        (__attribute__((address_space(3))) unsigned int*)l, 4, 0, 0);
}

// ---------------- K1: fused prep, async-DMA double-buffered chunks -----------------------
// grid (64 p, 4 b) x 512: block = one p-row (64 q), all 128 c in 8 chunks of 16.
__global__ void __launch_bounds__(512) prep(const float* __restrict__ x,
                     unsigned short* __restrict__ kmat,
                     unsigned short* __restrict__ kT,
                     unsigned short* __restrict__ xbT) {
    const int p = blockIdx.x, b = blockIdx.y;
    const int t = threadIdx.x, wave = t >> 6, lane = t & 63;

    __shared__ float sX[2][16][3][66];    // double-buffered chunk: 16 ch x 3 rows x 64+halo
    __shared__ float sMidT[64 * 132];     // [q][c], f32, stride 132
    __shared__ __align__(16) unsigned short sQ[64 * 136];
    __shared__ float sqp[512];
    __shared__ float sInv[64];

    // zero the q-halo columns once (DMA only ever writes elements [1..64])
    if (t < 192) {
        int bu = t / 96, u = t % 96, side = u & 1, v = u >> 1;   // v < 48
        int r = v % 3, cc = v / 3;
        sX[bu][cc][r][side * 65] = 0.f;
    }

    // issue chunk 0 DMA (wave-uniform (cc,r) per issue; 1 row = 64 lanes x 4B)
#pragma unroll
    for (int i = 0; i < 6; i++) {
        int pair = wave * 6 + i;
        int cc = pair / 3, r = pair - cc * 3, pp = p + r - 1;
        if ((unsigned)pp < 64u)
            gl_lds4(x + ((size_t)(b * 128 + cc) * 4096 + pp * 64) + lane,
                    &sX[0][cc][r][1]);
        else
            sX[0][cc][r][1 + lane] = 0.f;
    }

    float sqacc = 0.f;
    for (int k = 0; k < 8; k++) {
        __syncthreads();                              // chunk k DMA + writes drained
        if (k < 7) {                                  // issue chunk k+1 into other buffer
            int c0n = (k + 1) * 16, bn = (k + 1) & 1;
#pragma unroll
            for (int i = 0; i < 6; i++) {
                int pair = wave * 6 + i;
                int cc = pair / 3, r = pair - cc * 3, pp = p + r - 1;
                if ((unsigned)pp < 64u)
                    gl_lds4(x + ((size_t)(b * 128 + c0n + cc) * 4096 + pp * 64) + lane,
                            &sX[bn][cc][r][1]);
                else
                    sX[bn][cc][r][1 + lane] = 0.f;
            }
        }
        const int c0 = k * 16, kb = k & 1;
#pragma unroll
        for (int j = 0; j < 2; j++) {
            int cc = wave * 2 + j;
            float mid = sX[kb][cc][1][1 + lane] + 1e-7f;
            sMidT[lane * 132 + c0 + cc] = mid;
            sqacc += mid * mid;
            float sbox = 0.f;
#pragma unroll
            for (int r = 0; r < 3; r++)
                sbox += sX[kb][cc][r][lane] + sX[kb][cc][r][lane + 1] + sX[kb][cc][r][lane + 2];
            sQ[lane * 136 + c0 + cc] = f2bf(sbox * L2E);
        }
    }
    sqp[t] = sqacc;
    __syncthreads();
    if (t < 64) {
        float s = 0.f;
#pragma unroll
        for (int w = 0; w < 8; w++) s += sqp[w * 64 + t];
        sInv[t] = rsqrtf(s);
    }
    __syncthreads();

    // xbT rows: raw (1024 (row,g) pairs, 2 iters @ 512 thr)
#pragma unroll
    for (int i = 0; i < 2; i++) {
        int u = i * 512 + t, row = u >> 4, g = u & 15;
        *(bf16x8*)(xbT + ((size_t)b * 4096 + p * 64 + row) * 128 + g * 8) =
            *(const bf16x8*)(sQ + row * 136 + g * 8);
    }
    // kmat rows: 16B chunk G stored at G ^ (q&15)  (key&15 == q&15)
#pragma unroll
    for (int i = 0; i < 2; i++) {
        int u = i * 512 + t, q = u >> 4, G = u & 15;
        float iv = sInv[q];
        f32x4 a = *(const f32x4*)(sMidT + q * 132 + G * 8);
        f32x4 c = *(const f32x4*)(sMidT + q * 132 + G * 8 + 4);
        unsigned int w[4];
        w[0] = pk_bf16(a[0] * iv, a[1] * iv);
        w[1] = pk_bf16(a[2] * iv, a[3] * iv);
        w[2] = pk_bf16(c[0] * iv, c[1] * iv);
        w[3] = pk_bf16(c[2] * iv, c[3] * iv);
        int Gs = G ^ (q & 15);
        *(uint4*)(kmat + ((size_t)b * 4096 + p * 64 + q) * 128 + Gs * 8) =
            make_uint4(w[0], w[1], w[2], w[3]);
    }
    // kT rows: within each 64-key tile, 8-key chunk h stored at h ^ (c&7) (512 pairs, 1 iter)
    {
        int cl = t >> 2, qg = t & 3;
        unsigned int w[8];
#pragma unroll
        for (int j = 0; j < 8; j++) {
            int ql = qg * 16 + j * 2;
            w[j] = pk_bf16(sMidT[ql * 132 + cl] * sInv[ql],
                           sMidT[(ql + 1) * 132 + cl] * sInv[ql + 1]);
        }
        unsigned short* dst = kT + ((size_t)b * 128 + cl) * 4096 + p * 64;
        int h0 = (qg * 2) ^ (cl & 7), h1 = (qg * 2 + 1) ^ (cl & 7);
        *(uint4*)(dst + h0 * 8) = make_uint4(w[0], w[1], w[2], w[3]);
        *(uint4*)(dst + h1 * 8) = make_uint4(w[4], w[5], w[6], w[7]);
    }
}

// ---------------- K2: split-K flash, 1 barrier/iter, private swizzled sP -----------------
#define BUF_STRIDE 16384               // u16: sK 8192 + sV 8192
#define SP_BASE    32768               // u16: sP 64 rows x 64 (per-wave 16 rows, h-shared)
#define SMEM_ELEMS 36864               // u16 = 73728 B -> 2 blocks/CU

__global__ void __launch_bounds__(256, 2) flash_attn(
        const unsigned short* __restrict__ kmat,
        const unsigned short* __restrict__ kT,
        const unsigned short* __restrict__ xbT,
        unsigned short* __restrict__ opart,
        float* __restrict__ lsum,
        int nsplit, int qbshift) {
    const int combo = blockIdx.x & (4 * nsplit - 1);
    const int qb = blockIdx.x >> qbshift;        // 128-query tile, 0..31
    const int b = combo & 3, split = combo >> 2;
    const int nk = 4096 / nsplit, NIT = nk >> 6, kt_base = split * nk;
    const int t = threadIdx.x;
    const int wave = t >> 6, lane = t & 63;
    const int l16 = lane & 15, quad = lane >> 4;

    __shared__ __align__(16) unsigned short smem[SMEM_ELEMS];

    // Q frags (B-operand of S^T): B[n=q=l16][k=c=quad*8+j]
    bf16x8 aq[2][4];
#pragma unroll
    for (int h = 0; h < 2; h++) {
        const unsigned short* xq =
            xbT + ((size_t)b * 4096 + qb * 128 + wave * 32 + h * 16 + l16) * 128 + quad * 8;
#pragma unroll
        for (int cc = 0; cc < 4; cc++) aq[h][cc] = *(const bf16x8*)(xq + cc * 32);
    }

    f32x4 o[2][8];
#pragma unroll
    for (int h = 0; h < 2; h++)
#pragma unroll
        for (int n = 0; n < 8; n++) o[h][n] = (f32x4){0.f, 0.f, 0.f, 0.f};
    float rs[2] = {0.f, 0.f};

    const unsigned short* kmb = kmat + (size_t)b * 4096 * 128;
    const unsigned short* ktb = kT + (size_t)b * 128 * 4096;

    // preload tile 0 into buffer 0
    {
        const unsigned short* gK = kmb + (size_t)kt_base * 128;
#pragma unroll
        for (int i = 0; i < 4; i++) {
            int e = i * 2048 + t * 8;
            gl_lds16(gK + e, smem + i * 2048 + wave * 512);
            gl_lds16(ktb + (size_t)(e >> 6) * 4096 + kt_base + (e & 63),
                     smem + 8192 + i * 2048 + wave * 512);
        }
    }

    // per-wave-private sP row base: row = wave*16 + l16, stride 64 u16 (128 B)
    unsigned short* const sP = smem + SP_BASE + (wave * 16 + l16) * 64;

    for (int it = 0; it < NIT; it++) {
        const int base = (it & 1) * BUF_STRIDE;
        unsigned short* sK = smem + base;                 // [64 keys][128], swizzled chunks
        unsigned short* sV = smem + base + 8192;          // [128 c][64], swizzled chunks

        // sole barrier: drains this tile's DMA (own vmcnt(0)); all waves past it ->
        // all reads of the OTHER buffer (prev iter) retired -> safe to DMA into it.
        __syncthreads();

        // issue next tile's DMA immediately: latency window = QK + softmax + PV
        if (it + 1 < NIT) {
            const int kt0 = kt_base + (it + 1) * 64;
            unsigned short* nb = smem + ((it + 1) & 1) * BUF_STRIDE;
            const unsigned short* gK = kmb + (size_t)kt0 * 128;
#pragma unroll
            for (int i = 0; i < 4; i++) {
                int e = i * 2048 + t * 8;
                gl_lds16(gK + e, nb + i * 2048 + wave * 512);
                gl_lds16(ktb + (size_t)(e >> 6) * 4096 + kt0 + (e & 63),
                         nb + 8192 + i * 2048 + wave * 512);
            }
        }

        // S^T = K Q^T: lane holds S^T[key = k4*16 + quad*4 + r][q = l16]
        f32x4 s[2][4];
#pragma unroll
        for (int h = 0; h < 2; h++)
#pragma unroll
            for (int k4 = 0; k4 < 4; k4++) s[h][k4] = (f32x4){0.f, 0.f, 0.f, 0.f};
        __builtin_amdgcn_s_setprio(1);
#pragma unroll
        for (int cc = 0; cc < 4; cc++) {
#pragma unroll
            for (int k4 = 0; k4 < 4; k4++) {
                bf16x8 ak = *(const bf16x8*)(sK + (k4 * 16 + l16) * 128 +
                                             (((cc * 4 + quad) ^ l16) * 8));
                s[0][k4] = __builtin_amdgcn_mfma_f32_16x16x32_bf16(ak, aq[0][cc], s[0][k4], 0, 0, 0);
                s[1][k4] = __builtin_amdgcn_mfma_f32_16x16x32_bf16(ak, aq[1][cc], s[1][k4], 0, 0, 0);
            }
        }
        __builtin_amdgcn_s_setprio(0);

        // p = 2^s; lane-local row-sum; b64-pack consecutive keys -> private sP.
        // h=0/1 time-share the same sP row (per-wave DS ops are in-order).
        // 16B-slot XOR swizzle (slot ^ (l16&7)): write b64 and read b128 both at bank-min.
        bf16x8 pa[2][2];
#pragma unroll
        for (int h = 0; h < 2; h++) {
#pragma unroll
            for (int k4 = 0; k4 < 4; k4++) {
                float p0 = __builtin_amdgcn_exp2f(s[h][k4][0]);
                float p1 = __builtin_amdgcn_exp2f(s[h][k4][1]);
                float p2 = __builtin_amdgcn_exp2f(s[h][k4][2]);
                float p3 = __builtin_amdgcn_exp2f(s[h][k4][3]);
                rs[h] += (p0 + p1) + (p2 + p3);
                u32x2 d;
                d[0] = pk_bf16(p0, p1);
                d[1] = pk_bf16(p2, p3);
                *(u32x2*)(sP + ((k4 * 2 + (quad >> 1)) ^ (l16 & 7)) * 8 + (quad & 1) * 4) = d;
            }
            asm volatile("" ::: "memory");
#pragma unroll
            for (int kc = 0; kc < 2; kc++)
                pa[h][kc] = *(const bf16x8*)(sP + ((kc * 4 + quad) ^ (l16 & 7)) * 8);
            asm volatile("" ::: "memory");
        }

        // O += P V : swizzled sV chunk read (c&7 == l16&7)
        __builtin_amdgcn_s_setprio(1);
#pragma unroll
        for (int kc = 0; kc < 2; kc++)
#pragma unroll
            for (int n = 0; n < 8; n++) {
                bf16x8 bv = *(const bf16x8*)(sV + (n * 16 + l16) * 64 +
                                             (((kc * 4 + quad) ^ (l16 & 7)) * 8));
                o[0][n] = __builtin_amdgcn_mfma_f32_16x16x32_bf16(pa[0][kc], bv, o[0][n], 0, 0, 0);
                o[1][n] = __builtin_amdgcn_mfma_f32_16x16x32_bf16(pa[1][kc], bv, o[1][n], 0, 0, 0);
            }
        __builtin_amdgcn_s_setprio(0);
    }

    // row-sums reduce across quads; store lsum
#pragma unroll
    for (int h = 0; h < 2; h++) {
        rs[h] += __shfl_xor(rs[h], 16);
        rs[h] += __shfl_xor(rs[h], 32);
    }
    if (lane < 16) {
#pragma unroll
        for (int h = 0; h < 2; h++)
            lsum[(size_t)(split * 4 + b) * 4096 + qb * 128 + wave * 32 + h * 16 + lane] = rs[h];
    }

    // single-pass bf16 epilogue: sO [128 c][136] u16 = 17408 (aliases smem)
    __syncthreads();
    unsigned short* sO = smem;
    unsigned int* sO32 = (unsigned int*)smem;
#pragma unroll
    for (int h = 0; h < 2; h++)
#pragma unroll
        for (int n = 0; n < 8; n++) {
            int c = n * 16 + l16;
            int q = wave * 32 + h * 16 + quad * 4;     // even -> >>1 exact
            sO32[(c * 136 + q) >> 1] = pk_bf16(o[h][n][0], o[h][n][1]);
            sO32[(c * 136 + q + 2) >> 1] = pk_bf16(o[h][n][2], o[h][n][3]);
        }
    __syncthreads();
#pragma unroll
    for (int i = 0; i < 8; i++) {
        int u = i * 256 + t, c = u >> 4, chunk = u & 15;
        *(uint4*)(opart + ((size_t)(split * 4 + b) * 128 + c) * 4096 + qb * 128 + chunk * 8) =
            *(const uint4*)(sO + c * 136 + chunk * 8);
    }
}

// ---------------- K3: combine splits + mask blend ----------------------------------------
// grid (64 qb64, 4 b, 2 cz) x 256: block = 64 q x 64 c.
__global__ void combine(const unsigned short* __restrict__ opart,
                        const float* __restrict__ lsum,
                        const float* __restrict__ x,
                        const float* __restrict__ mask,
                        float* __restrict__ out, int S) {
    const int qb = blockIdx.x, b = blockIdx.y, cz = blockIdx.z, t = threadIdx.x;
    __shared__ float Linv[64];
    if (t < 64) {
        float L = 0.f;
        for (int s2 = 0; s2 < S; s2++)
            L += lsum[(size_t)(s2 * 4 + b) * 4096 + qb * 64 + t];
        Linv[t] = 1.f / fmaxf(L, 1e-37f);
    }
    __syncthreads();
#pragma unroll
    for (int i = 0; i < 2; i++) {
        int u = i * 256 + t, c = cz * 64 + (u >> 3), qc = u & 7;
        size_t qoff = (size_t)qb * 64 + qc * 8;
        const unsigned short* ob = opart + ((size_t)b * 128 + c) * 4096 + qoff;
        float acc[8];
        if (S == 4) {               // all 4 split loads issued together (independent)
            u16x8 p0 = *(const u16x8*)(ob);
            u16x8 p1 = *(const u16x8*)(ob + (size_t)1 * 2097152);
            u16x8 p2 = *(const u16x8*)(ob + (size_t)2 * 2097152);
            u16x8 p3 = *(const u16x8*)(ob + (size_t)3 * 2097152);
#pragma unroll
            for (int j = 0; j < 8; j++)
                acc[j] = (bf2f(p0[j]) + bf2f(p1[j])) + (bf2f(p2[j]) + bf2f(p3[j]));
        } else {                    // S == 2
            u16x8 p0 = *(const u16x8*)(ob);
            u16x8 p1 = *(const u16x8*)(ob + (size_t)1 * 2097152);
#pragma unroll
            for (int j = 0; j < 8; j++)
                acc[j] = bf2f(p0[j]) + bf2f(p1[j]);
        }
        const float* xr = x + ((size_t)b * 128 + c) * 4096 + qoff;
        const float* mr = mask + (size_t)b * 4096 + qoff;
        float* outr = out + ((size_t)b * 128 + c) * 4096 + qoff;
#pragma unroll
        for (int half = 0; half < 2; half++) {
            f32x4 xv = *(const f32x4*)(xr + half * 4);
            f32x4 mv = *(const f32x4*)(mr + half * 4);
            f32x4 res;
#pragma unroll
            for (int j = 0; j < 4; j++)
                res[j] = acc[half * 4 + j] * Linv[qc * 8 + half * 4 + j] *
                         (1.f - mv[j]) * (1.f / 9.f) + xv[j] * mv[j];
            *(f32x4*)(outr + half * 4) = res;
        }
    }
}

extern "C" void kernel_launch(void* const* d_in, const int* in_sizes, int n_in,
                              void* d_out, int out_size, void* d_ws, size_t ws_size,
                              hipStream_t stream) {
    const float* x = (const float*)d_in[0];     // f32 (4,128,64,64)
    const float* mask = (const float*)d_in[1];  // f32 (4,1,64,64)
    float* out = (float*)d_out;                 // f32 (4,128,64,64)
    char* ws = (char*)d_ws;
    unsigned short* kmat = (unsigned short*)(ws);
    unsigned short* kT   = (unsigned short*)(ws + (size_t)4 * 1024 * 1024);
    unsigned short* xbT  = (unsigned short*)(ws + (size_t)8 * 1024 * 1024);
    float* lsum          = (float*)(ws + (size_t)12 * 1024 * 1024);
    unsigned short* opart = (unsigned short*)(ws + (size_t)13 * 1024 * 1024);

    // ws need: 13 MiB + S*4 MiB
    int S, qbshift;
    if (ws_size >= (size_t)29 * 1024 * 1024)      { S = 4; qbshift = 4; }
    else if (ws_size >= (size_t)21 * 1024 * 1024) { S = 2; qbshift = 3; }
    else return;

    prep<<<dim3(64, 4), 512, 0, stream>>>(x, kmat, kT, xbT);
    flash_attn<<<dim3(32 * 4 * S), 256, 0, stream>>>(kmat, kT, xbT, opart, lsum, S, qbshift);
    combine<<<dim3(64, 4, 2), 256, 0, stream>>>(opart, lsum, x, mask, out, S);
}